// Round 9
// baseline (320.197 us; speedup 1.0000x reference)
//
#include <hip/hip_runtime.h>

// PathGNNLayers: per-edge MLP + scatter-max GNN layer.
//   x:[N,32] f32, edge_index:[2,E] int32, edge_attr:[E,32] f32
//   W1:[96,64], b1:[64], W2:[64,32], b2:[32]
//   out[n] = max( x[n, -32:], max_{e: col[e]==n} MLP(x[row_e], x[col_e], ea[e]) )
//
// R9: CSR build without scattered-write amplification.
//   scatter_bin: bin=col>>6, sequential positions per bin -> L2-friendly writes
//   sort_bin:    one block per bin counting-sorts into final rc8 (8B records)
// Fused MFMA kernel (128 CSR-ordered edges/block) unchanged from R8 except
// rc8 packing and XCD-bijective block swizzle.

constexpr int XD   = 32;
constexpr int HID  = 64;
constexpr int OUTD = 32;
constexpr int BM   = 128;   // edges per block (MFMA kernel)
constexpr int ASTR = 104;   // A LDS stride in bf16 units
constexpr int HSTR = 72;    // H LDS stride in bf16 units
constexpr int VSTR = 40;    // V staging stride in bf16 units
constexpr int SCAN_CHUNK = 1024;  // elements per scan1 block (256 thr x 4)
constexpr int BIN_SHIFT  = 6;     // 64 nodes per bin

typedef __attribute__((ext_vector_type(8)))  short    short8;
typedef __attribute__((ext_vector_type(4)))  float    f32x4;
typedef __attribute__((ext_vector_type(4)))  float    floatx4;

static __device__ __forceinline__ unsigned f2bf(float f) {
    union { float f; unsigned u; } x; x.f = f;
    unsigned r = x.u + 0x7fff + ((x.u >> 16) & 1);   // RNE; finite inputs
    return r >> 16;
}

// float atomic-max via monotone integer encoding (exact, order-independent)
static __device__ __forceinline__ void atomax_f32(float* addr, float v) {
    if (v >= 0.0f) atomicMax(reinterpret_cast<int*>(addr), __float_as_int(v));
    else           atomicMin(reinterpret_cast<unsigned*>(addr), __float_as_uint(v));
}

// ---- init: out = x (residual + empty-segment floor), degree = 0 ----
__global__ __launch_bounds__(256) void init_out_deg(
    const float* __restrict__ x, float* __restrict__ out,
    unsigned* __restrict__ degree, int n_nodes, int total4)
{
    const int i = blockIdx.x * 256 + threadIdx.x;
    if (i < total4)
        reinterpret_cast<float4*>(out)[i] = reinterpret_cast<const float4*>(x)[i];
    if (i < n_nodes) degree[i] = 0u;
}

// ---- prep: degree count + x->bf16 + W1/W2 -> bf16 MFMA B-fragment order ----
__global__ __launch_bounds__(256) void prep_count(
    const float* __restrict__ x, unsigned* __restrict__ xbf,
    const int* __restrict__ ei,  unsigned* __restrict__ degree,
    const float* __restrict__ W1, const float* __restrict__ W2,
    unsigned* __restrict__ w1s, unsigned* __restrict__ w2s,
    int n_edges, int total8)
{
    const int i = blockIdx.x * 256 + threadIdx.x;

    if (i < n_edges) atomicAdd(&degree[ei[n_edges + i]], 1u);

    if (i < total8) {                      // x (f32) -> xbf (bf16), 8 floats/thread
        const float4* src = reinterpret_cast<const float4*>(x) + (size_t)i * 2;
        float4 a = src[0], b = src[1];
        uint4 o;
        o.x = f2bf(a.x) | (f2bf(a.y) << 16);
        o.y = f2bf(a.z) | (f2bf(a.w) << 16);
        o.z = f2bf(b.x) | (f2bf(b.y) << 16);
        o.w = f2bf(b.z) | (f2bf(b.w) << 16);
        reinterpret_cast<uint4*>(xbf)[i] = o;
    }

    // B-frag for tile (nt,ks): lane l holds B[k=ks*32+(l>>4)*8+j][col=nt*16+(l&15)]
    if (i < 768) {                         // W1: 4 nt x 3 ks x 64 lanes
        const int ti = i >> 6, lane = i & 63;
        const int nt = ti / 3, ks = ti % 3;
        const int col = nt * 16 + (lane & 15);
        const int k0  = ks * 32 + ((lane >> 4) << 3);
        unsigned o[4];
#pragma unroll
        for (int p = 0; p < 4; ++p)
            o[p] = f2bf(W1[(k0 + 2 * p) * HID + col]) |
                   (f2bf(W1[(k0 + 2 * p + 1) * HID + col]) << 16);
        reinterpret_cast<uint4*>(w1s)[i] = make_uint4(o[0], o[1], o[2], o[3]);
    } else if (i < 1024) {                 // W2: 2 nt x 2 ks x 64 lanes
        const int tt = i - 768;
        const int ti = tt >> 6, lane = tt & 63;
        const int nt = ti >> 1, ks = ti & 1;
        const int col = nt * 16 + (lane & 15);
        const int k0  = ks * 32 + ((lane >> 4) << 3);
        unsigned o[4];
#pragma unroll
        for (int p = 0; p < 4; ++p)
            o[p] = f2bf(W2[(k0 + 2 * p) * OUTD + col]) |
                   (f2bf(W2[(k0 + 2 * p + 1) * OUTD + col]) << 16);
        reinterpret_cast<uint4*>(w2s)[tt] = make_uint4(o[0], o[1], o[2], o[3]);
    }
}

// ---- hierarchical exclusive scan over degree[N] ----
__global__ __launch_bounds__(256) void scan1(
    const unsigned* __restrict__ degree, unsigned* __restrict__ start,
    unsigned* __restrict__ bsums, int n)
{
    __shared__ unsigned ts[256];
    const int t  = threadIdx.x;
    const int i0 = blockIdx.x * SCAN_CHUNK + t * 4;

    unsigned d0 = 0, d1 = 0, d2 = 0, d3 = 0;
    if (i0 + 3 < n) {
        uint4 d = *reinterpret_cast<const uint4*>(degree + i0);
        d0 = d.x; d1 = d.y; d2 = d.z; d3 = d.w;
    } else {
        if (i0     < n) d0 = degree[i0];
        if (i0 + 1 < n) d1 = degree[i0 + 1];
        if (i0 + 2 < n) d2 = degree[i0 + 2];
        if (i0 + 3 < n) d3 = degree[i0 + 3];
    }
    ts[t] = d0 + d1 + d2 + d3;
    __syncthreads();
#pragma unroll
    for (int off = 1; off < 256; off <<= 1) {
        unsigned val = (t >= off) ? ts[t - off] : 0u;
        __syncthreads();
        ts[t] += val;
        __syncthreads();
    }
    const unsigned excl = (t == 0) ? 0u : ts[t - 1];
    const unsigned e0 = excl, e1 = e0 + d0, e2 = e1 + d1, e3 = e2 + d2;
    if (i0 + 3 < n) {
        *reinterpret_cast<uint4*>(start + i0) = make_uint4(e0, e1, e2, e3);
    } else {
        if (i0     < n) start[i0]     = e0;
        if (i0 + 1 < n) start[i0 + 1] = e1;
        if (i0 + 2 < n) start[i0 + 2] = e2;
        if (i0 + 3 < n) start[i0 + 3] = e3;
    }
    if (t == 255) bsums[blockIdx.x] = ts[255];
}

// scan3: wave-reduce bsums prefix, apply offsets, write start/cursor/bcur.
__global__ __launch_bounds__(256) void scan3(
    unsigned* __restrict__ start, unsigned* __restrict__ cursor,
    unsigned* __restrict__ bcur,
    const unsigned* __restrict__ bsums, int n, int nb)
{
    __shared__ unsigned spre[2];
    const int t = threadIdx.x;
    const int c = (blockIdx.x * 256) / SCAN_CHUNK;   // block spans one chunk

    if (t < 64) {
        unsigned vc = 0, va = 0;
        for (int b = t; b < nb; b += 64) {
            const unsigned s = bsums[b];
            va += s;
            if (b < c) vc += s;
        }
#pragma unroll
        for (int o = 32; o; o >>= 1) {
            vc += __shfl_down(vc, o, 64);
            va += __shfl_down(va, o, 64);
        }
        if (t == 0) { spre[0] = vc; spre[1] = va; }
    }
    __syncthreads();

    const int i = blockIdx.x * 256 + t;
    if (i < n) {
        const unsigned v = start[i] + spre[0];
        start[i]  = v;
        cursor[i] = v;
        if ((i & ((1 << BIN_SHIFT) - 1)) == 0) bcur[i >> BIN_SHIFT] = v;
    } else if (i == n) {
        start[n] = spre[1];
    }
}

// pass 1: bin by col>>BIN_SHIFT; sequential positions per bin => L2-local writes
__global__ __launch_bounds__(256) void scatter_bin(
    const int* __restrict__ ei, unsigned* __restrict__ bcur,
    uint2* __restrict__ binned, int n_edges)
{
    int e = blockIdx.x * 256 + threadIdx.x;
    if (e >= n_edges) return;
    const unsigned row = (unsigned)ei[e];
    const unsigned col = (unsigned)ei[n_edges + e];
    const unsigned pos = atomicAdd(&bcur[col >> BIN_SHIFT], 1u);
    binned[pos] = make_uint2((row << 16) | col, (unsigned)e);
}

// pass 2: one block per bin; counting-sort bin slice into final rc8 using
// per-node cursors. Each block writes only its own contiguous window.
__global__ __launch_bounds__(256) void sort_bin(
    const unsigned* __restrict__ start, unsigned* __restrict__ cursor,
    const uint2* __restrict__ binned, uint2* __restrict__ rc8, int n_nodes)
{
    const int b  = blockIdx.x;
    const int n0 = b << BIN_SHIFT;
    const int n1 = min(n0 + (1 << BIN_SHIFT), n_nodes);
    const unsigned lo = start[n0];
    const unsigned hi = start[n1];
    for (unsigned i = lo + threadIdx.x; i < hi; i += 256) {
        const uint2 r = binned[i];
        const unsigned col = r.x & 0xffffu;
        const unsigned pos = atomicAdd(&cursor[col], 1u);
        rc8[pos] = r;
    }
}

// ---- fused: per-128-CSR-position MFMA MLP + segmented scatter-max ----
__global__ __launch_bounds__(256) void edge_mlp_fused(
    const unsigned* __restrict__ xbf,   // [N][16] u32 = [N][32] bf16
    const uint2*    __restrict__ rc8,   // [E] {(row<<16)|col, e} in CSR order
    const float*    __restrict__ ea,
    const unsigned* __restrict__ w1s,   // [12][64] x 16B frags
    const unsigned* __restrict__ w2s,   // [4][64] x 16B frags
    const float*    __restrict__ b1,
    const float*    __restrict__ b2,
    float*          __restrict__ out,   // [N][32] f32, pre-init to x
    int n_edges, int nwg)
{
    __shared__ alignas(16) unsigned short Albs[BM * ASTR];
    __shared__ alignas(16) unsigned short Hlds[BM * HSTR];
    __shared__ unsigned rcsE[BM];
    __shared__ unsigned rcsR[BM];
    __shared__ unsigned rcsC[BM];

    const int t    = threadIdx.x;
    const int lane = t & 63;
    const int wave = t >> 6;

    // XCD-bijective swizzle (m204): contiguous CSR ranges per XCD -> L2 locality
    int bid;
    {
        const int orig = blockIdx.x;
        const int q = nwg >> 3, r = nwg & 7;
        const int xcd = orig & 7, base8 = orig >> 3;
        bid = (xcd < r ? xcd * (q + 1) : r * (q + 1) + (xcd - r) * q) + base8;
    }
    const int base = bid * BM;

    // phase 0: load CSR records (padded rows clamp to last edge; duplicates
    // are harmless because max is idempotent)
    if (t < BM) {
        int p = base + t; if (p >= n_edges) p = n_edges - 1;
        const uint2 q = rc8[p];
        rcsE[t] = q.y; rcsR[t] = q.x >> 16; rcsC[t] = q.x & 0xffffu;
    }
    __syncthreads();

    // stage A[:, 0:64]: gather endpoint rows (thread = (edge m, side))
    {
        const int m    = t & 127;
        const int side = t >> 7;                    // 0 -> x[row], 1 -> x[col]
        const unsigned id = side ? rcsC[m] : rcsR[m];
        const uint4* src = reinterpret_cast<const uint4*>(xbf + (size_t)id * 16);
#pragma unroll
        for (int q = 0; q < 4; ++q)
            *reinterpret_cast<uint4*>(&Albs[m * ASTR + side * 32 + q * 8]) = src[q];
    }
    // stage A[:, 64:96]: ea rows gathered by edge id, f32->bf16
    {
#pragma unroll
        for (int i = 0; i < 4; ++i) {
            const int f = t + i * 256;
            const int m = f >> 3;
            const int c = (f & 7) * 4;
            const unsigned e = rcsE[m];
            const floatx4 d = __builtin_nontemporal_load(
                reinterpret_cast<const floatx4*>(ea + (size_t)e * 32 + c));
            uint2 pk;
            pk.x = f2bf(d.x) | (f2bf(d.y) << 16);
            pk.y = f2bf(d.z) | (f2bf(d.w) << 16);
            *reinterpret_cast<uint2*>(&Albs[m * ASTR + 64 + c]) = pk;
        }
    }

    short8 w1f[12];
#pragma unroll
    for (int ti = 0; ti < 12; ++ti)
        w1f[ti] = *reinterpret_cast<const short8*>(w1s + (size_t)(ti * 64 + lane) * 4);
    float bb1[4];
#pragma unroll
    for (int nt = 0; nt < 4; ++nt) bb1[nt] = b1[nt * 16 + (lane & 15)];

    __syncthreads();

    // layer 1: [128x96] @ [96x64]
    f32x4 acc1[2][4];
#pragma unroll
    for (int mi = 0; mi < 2; ++mi)
#pragma unroll
        for (int nt = 0; nt < 4; ++nt) acc1[mi][nt] = (f32x4){0.f, 0.f, 0.f, 0.f};

#pragma unroll
    for (int ks = 0; ks < 3; ++ks) {
#pragma unroll
        for (int mi = 0; mi < 2; ++mi) {
            const int mt = wave * 2 + mi;
            short8 afrag = *reinterpret_cast<const short8*>(
                &Albs[(mt * 16 + (lane & 15)) * ASTR + ks * 32 + ((lane >> 4) << 3)]);
#pragma unroll
            for (int nt = 0; nt < 4; ++nt)
                acc1[mi][nt] = __builtin_amdgcn_mfma_f32_16x16x32_bf16(
                    afrag, w1f[nt * 3 + ks], acc1[mi][nt], 0, 0, 0);
        }
    }

    // bias + ReLU -> H (bf16, LDS). C layout: col=lane&15, row=(lane>>4)*4+r.
#pragma unroll
    for (int mi = 0; mi < 2; ++mi) {
        const int mt = wave * 2 + mi;
#pragma unroll
        for (int nt = 0; nt < 4; ++nt)
#pragma unroll
            for (int r = 0; r < 4; ++r) {
                const float h = fmaxf(acc1[mi][nt][r] + bb1[nt], 0.0f);
                Hlds[(mt * 16 + ((lane >> 4) << 2) + r) * HSTR + nt * 16 + (lane & 15)] =
                    (unsigned short)f2bf(h);
            }
    }

    short8 w2f[4];
#pragma unroll
    for (int ti = 0; ti < 4; ++ti)
        w2f[ti] = *reinterpret_cast<const short8*>(w2s + (size_t)(ti * 64 + lane) * 4);
    float bb2[2];
#pragma unroll
    for (int nt = 0; nt < 2; ++nt) bb2[nt] = b2[nt * 16 + (lane & 15)];

    __syncthreads();

    // layer 2: [128x64] @ [64x32]
    f32x4 acc2[2][2];
#pragma unroll
    for (int mi = 0; mi < 2; ++mi)
#pragma unroll
        for (int nt = 0; nt < 2; ++nt) acc2[mi][nt] = (f32x4){0.f, 0.f, 0.f, 0.f};

#pragma unroll
    for (int ks = 0; ks < 2; ++ks) {
#pragma unroll
        for (int mi = 0; mi < 2; ++mi) {
            const int mt = wave * 2 + mi;
            short8 hfrag = *reinterpret_cast<const short8*>(
                &Hlds[(mt * 16 + (lane & 15)) * HSTR + ks * 32 + ((lane >> 4) << 3)]);
#pragma unroll
            for (int nt = 0; nt < 2; ++nt)
                acc2[mi][nt] = __builtin_amdgcn_mfma_f32_16x16x32_bf16(
                    hfrag, w2f[nt * 2 + ks], acc2[mi][nt], 0, 0, 0);
        }
    }

    // bias, V (bf16) -> LDS (reuse Albs)
    unsigned short* Vlds = Albs;
#pragma unroll
    for (int mi = 0; mi < 2; ++mi) {
        const int mt = wave * 2 + mi;
#pragma unroll
        for (int nt = 0; nt < 2; ++nt)
#pragma unroll
            for (int r = 0; r < 4; ++r) {
                const float val = acc2[mi][nt][r] + bb2[nt];
                Vlds[(mt * 16 + ((lane >> 4) << 2) + r) * VSTR + nt * 16 + (lane & 15)] =
                    (unsigned short)f2bf(val);
            }
    }
    __syncthreads();

    // segmented max: 8 groups x 32 lanes; group g walks rows [g*16, g*16+16).
    // CSR order => equal node ids are adjacent; flush on change (idempotent max
    // via atomics tolerates duplicates/non-monotonicity).
    {
        const int g  = t >> 5;
        const int j  = t & 31;
        const int r0 = g * 16;

        unsigned ncur = rcsC[r0];
        float mv = __uint_as_float((unsigned)Vlds[r0 * VSTR + j] << 16);
#pragma unroll
        for (int r = 1; r < 16; ++r) {
            const unsigned nd = rcsC[r0 + r];
            const float val = __uint_as_float((unsigned)Vlds[(r0 + r) * VSTR + j] << 16);
            if (nd != ncur) {
                atomax_f32(out + (size_t)ncur * OUTD + j, mv);
                ncur = nd;
                mv = val;
            } else {
                mv = fmaxf(mv, val);
            }
        }
        atomax_f32(out + (size_t)ncur * OUTD + j, mv);
    }
}

extern "C" void kernel_launch(void* const* d_in, const int* in_sizes, int n_in,
                              void* d_out, int out_size, void* d_ws, size_t ws_size,
                              hipStream_t stream)
{
    const float* x  = (const float*)d_in[0];
    const int*   ei = (const int*)  d_in[1];
    const float* ea = (const float*)d_in[2];
    const float* W1 = (const float*)d_in[3];
    const float* b1 = (const float*)d_in[4];
    const float* W2 = (const float*)d_in[5];
    const float* b2 = (const float*)d_in[6];
    float* out = (float*)d_out;

    const int n_nodes = in_sizes[0] / XD;
    const int n_edges = in_sizes[2] / 32;
    const int nb_scan = (n_nodes + SCAN_CHUNK - 1) / SCAN_CHUNK;
    const int nbins   = (n_nodes + (1 << BIN_SHIFT) - 1) >> BIN_SHIFT;

    // ws: degree[N] | cursor[N] | start[N+1] | bsums | bcur[nbins] |
    //     binned[E] uint2 | rc8[E] uint2 | xbf | w1s | w2s
    size_t off = 0;
    unsigned* degree = (unsigned*)((char*)d_ws + off); off += (size_t)n_nodes * 4;
    unsigned* cursor = (unsigned*)((char*)d_ws + off); off += (size_t)n_nodes * 4;
    unsigned* startp = (unsigned*)((char*)d_ws + off); off += (size_t)(n_nodes + 1) * 4;
    unsigned* bsums  = (unsigned*)((char*)d_ws + off); off += (size_t)(nb_scan + 1) * 4;
    unsigned* bcur   = (unsigned*)((char*)d_ws + off); off += (size_t)nbins * 4;
    off = (off + 15) & ~(size_t)15;
    uint2*    binned = (uint2*)   ((char*)d_ws + off); off += (size_t)n_edges * 8;
    uint2*    rc8    = (uint2*)   ((char*)d_ws + off); off += (size_t)n_edges * 8;
    unsigned* xbf    = (unsigned*)((char*)d_ws + off); off += (size_t)n_nodes * 16 * 4;
    unsigned* w1s    = (unsigned*)((char*)d_ws + off); off += 768 * 16;
    unsigned* w2s    = (unsigned*)((char*)d_ws + off);

    const int total8 = n_nodes * XD / 8;
    const int total4 = n_nodes * OUTD / 4;
    const int nwg    = (n_edges + BM - 1) / BM;

    init_out_deg<<<(total4 + 255) / 256, 256, 0, stream>>>(x, out, degree, n_nodes, total4);
    prep_count<<<(n_edges + 255) / 256, 256, 0, stream>>>(
        x, xbf, ei, degree, W1, W2, w1s, w2s, n_edges, total8);
    scan1<<<nb_scan, 256, 0, stream>>>(degree, startp, bsums, n_nodes);
    scan3<<<(n_nodes + 256) / 256, 256, 0, stream>>>(
        startp, cursor, bcur, bsums, n_nodes, nb_scan);
    scatter_bin<<<(n_edges + 255) / 256, 256, 0, stream>>>(ei, bcur, binned, n_edges);
    sort_bin<<<nbins, 256, 0, stream>>>(startp, cursor, binned, rc8, n_nodes);
    edge_mlp_fused<<<nwg, 256, 0, stream>>>(
        xbf, rc8, ea, w1s, w2s, b1, b2, out, n_edges, nwg);
}

// Round 10
// 104.371 us; speedup vs baseline: 3.0679x; 3.0679x over previous
//
#include <hip/hip_runtime.h>

// PathGNNLayers: per-edge MLP + scatter-max GNN layer.
//   x:[N,32] f32, edge_index:[2,E] int32, edge_attr:[E,32] f32
//   W1:[96,64], b1:[64], W2:[64,32], b2:[32]
//   out[n] = max( x[n, -32:], max_{e: col[e]==n} MLP(x[row_e], x[col_e], ea[e]) )
//
// R10: atomic-free binned CSR build + bin-owned fused kernel.
//   bin_hist:  LDS histogram per 8192-edge chunk -> cnt[nblk][nbins]
//   bin_off:   per-bin scan over chunk counts -> off[nblk][nbins], totals
//   base_scan: exclusive scan of totals -> base[]
//   bin_write: LDS ranks; each (chunk,bin) run written by one CU (no amp)
//   fused:     one block per 64-node bin; LDS max-accumulator (monotone uint),
//              epilogue straight from MFMA regs, plain final stores. No global
//              atomics anywhere in the output path.

constexpr int XD   = 32;
constexpr int HID  = 64;
constexpr int OUTD = 32;
constexpr int BM   = 128;   // edges per MFMA tile
constexpr int ASTR = 104;   // A LDS stride in bf16 units
constexpr int HSTR = 72;    // H LDS stride in bf16 units
constexpr int BIN_SHIFT = 6;            // 64 nodes per bin
constexpr int BINW  = 1 << BIN_SHIFT;
constexpr int BLK_E = 8192;             // edges per histogram/write chunk
constexpr int EPB   = BLK_E / 256;      // edges per thread in chunk kernels

typedef __attribute__((ext_vector_type(8)))  short    short8;
typedef __attribute__((ext_vector_type(4)))  float    f32x4;
typedef __attribute__((ext_vector_type(4)))  float    floatx4;

static __device__ __forceinline__ unsigned f2bf(float f) {
    union { float f; unsigned u; } x; x.f = f;
    unsigned r = x.u + 0x7fff + ((x.u >> 16) & 1);   // RNE; finite inputs
    return r >> 16;
}
// monotone f32<->u32 encoding: enc order == float order (finite values)
static __device__ __forceinline__ unsigned encf(float f) {
    unsigned u = __float_as_uint(f);
    return (u >> 31) ? ~u : (u | 0x80000000u);
}
static __device__ __forceinline__ float decf(unsigned k) {
    return __uint_as_float((k >> 31) ? (k & 0x7fffffffu) : ~k);
}

// ---- prep: x->bf16 table + W1/W2 -> bf16 MFMA B-fragment order ----
__global__ __launch_bounds__(256) void prep(
    const float* __restrict__ x, unsigned* __restrict__ xbf,
    const float* __restrict__ W1, const float* __restrict__ W2,
    unsigned* __restrict__ w1s, unsigned* __restrict__ w2s, int total8)
{
    const int i = blockIdx.x * 256 + threadIdx.x;

    if (i < total8) {                      // x (f32) -> xbf (bf16), 8 floats/thread
        const float4* src = reinterpret_cast<const float4*>(x) + (size_t)i * 2;
        float4 a = src[0], b = src[1];
        uint4 o;
        o.x = f2bf(a.x) | (f2bf(a.y) << 16);
        o.y = f2bf(a.z) | (f2bf(a.w) << 16);
        o.z = f2bf(b.x) | (f2bf(b.y) << 16);
        o.w = f2bf(b.z) | (f2bf(b.w) << 16);
        reinterpret_cast<uint4*>(xbf)[i] = o;
    }

    // B-frag for tile (nt,ks): lane l holds B[k=ks*32+(l>>4)*8+j][col=nt*16+(l&15)]
    if (i < 768) {                         // W1: 4 nt x 3 ks x 64 lanes
        const int ti = i >> 6, lane = i & 63;
        const int nt = ti / 3, ks = ti % 3;
        const int col = nt * 16 + (lane & 15);
        const int k0  = ks * 32 + ((lane >> 4) << 3);
        unsigned o[4];
#pragma unroll
        for (int p = 0; p < 4; ++p)
            o[p] = f2bf(W1[(k0 + 2 * p) * HID + col]) |
                   (f2bf(W1[(k0 + 2 * p + 1) * HID + col]) << 16);
        reinterpret_cast<uint4*>(w1s)[i] = make_uint4(o[0], o[1], o[2], o[3]);
    } else if (i < 1024) {                 // W2: 2 nt x 2 ks x 64 lanes
        const int tt = i - 768;
        const int ti = tt >> 6, lane = tt & 63;
        const int nt = ti >> 1, ks = ti & 1;
        const int col = nt * 16 + (lane & 15);
        const int k0  = ks * 32 + ((lane >> 4) << 3);
        unsigned o[4];
#pragma unroll
        for (int p = 0; p < 4; ++p)
            o[p] = f2bf(W2[(k0 + 2 * p) * OUTD + col]) |
                   (f2bf(W2[(k0 + 2 * p + 1) * OUTD + col]) << 16);
        reinterpret_cast<uint4*>(w2s)[tt] = make_uint4(o[0], o[1], o[2], o[3]);
    }
}

// ---- pass 1: per-chunk LDS histogram over bins (no global atomics) ----
__global__ __launch_bounds__(256) void bin_hist(
    const int* __restrict__ ei, unsigned* __restrict__ cnt,
    int n_edges, int nbins)
{
    __shared__ unsigned lh[1024];          // nbins <= 1024
    const int t = threadIdx.x;
    for (int i = t; i < nbins; i += 256) lh[i] = 0u;
    __syncthreads();
    const int chunk = blockIdx.x * BLK_E;
#pragma unroll
    for (int i = 0; i < EPB; ++i) {
        const int e = chunk + i * 256 + t;
        if (e < n_edges)
            atomicAdd(&lh[((unsigned)ei[n_edges + e]) >> BIN_SHIFT], 1u);
    }
    __syncthreads();
    for (int i = t; i < nbins; i += 256)
        cnt[(size_t)blockIdx.x * nbins + i] = lh[i];
}

// ---- pass 2: per-bin exclusive scan over chunk counts (one block per bin) ----
__global__ __launch_bounds__(128) void bin_off(
    const unsigned* __restrict__ cnt, unsigned* __restrict__ off,
    unsigned* __restrict__ totals, int nblk, int nbins)
{
    __shared__ unsigned ts[128];           // nblk <= 128
    const int j = blockIdx.x;
    const int t = threadIdx.x;
    const unsigned d = (t < nblk) ? cnt[(size_t)t * nbins + j] : 0u;
    ts[t] = d;
    __syncthreads();
#pragma unroll
    for (int o = 1; o < 128; o <<= 1) {
        unsigned v = (t >= o) ? ts[t - o] : 0u;
        __syncthreads();
        ts[t] += v;
        __syncthreads();
    }
    if (t < nblk) off[(size_t)t * nbins + j] = ts[t] - d;   // exclusive
    if (t == 127) totals[j] = ts[127];
}

// ---- pass 3: exclusive scan of totals -> base[]; base[nbins] = E ----
__global__ __launch_bounds__(256) void base_scan(
    const unsigned* __restrict__ totals, unsigned* __restrict__ base, int nbins)
{
    __shared__ unsigned ts[256];           // supports nbins <= 1024
    const int t  = threadIdx.x;
    const int i0 = t * 4;
    unsigned d0 = (i0     < nbins) ? totals[i0]     : 0u;
    unsigned d1 = (i0 + 1 < nbins) ? totals[i0 + 1] : 0u;
    unsigned d2 = (i0 + 2 < nbins) ? totals[i0 + 2] : 0u;
    unsigned d3 = (i0 + 3 < nbins) ? totals[i0 + 3] : 0u;
    ts[t] = d0 + d1 + d2 + d3;
    __syncthreads();
#pragma unroll
    for (int o = 1; o < 256; o <<= 1) {
        unsigned v = (t >= o) ? ts[t - o] : 0u;
        __syncthreads();
        ts[t] += v;
        __syncthreads();
    }
    const unsigned excl = (t == 0) ? 0u : ts[t - 1];
    const unsigned e0 = excl, e1 = e0 + d0, e2 = e1 + d1, e3 = e2 + d2;
    if (i0     < nbins) base[i0]     = e0;
    if (i0 + 1 < nbins) base[i0 + 1] = e1;
    if (i0 + 2 < nbins) base[i0 + 2] = e2;
    if (i0 + 3 < nbins) base[i0 + 3] = e3;
    if (t == 255) base[nbins] = ts[255];
}

// ---- pass 4: write records; each (chunk,bin) run owned by one block ----
__global__ __launch_bounds__(256) void bin_write(
    const int* __restrict__ ei, const unsigned* __restrict__ off,
    const unsigned* __restrict__ base, uint2* __restrict__ rec,
    int n_edges, int nbins)
{
    __shared__ unsigned loff[1024];
    __shared__ unsigned lrank[1024];
    const int t = threadIdx.x;
    const int b = blockIdx.x;
    for (int i = t; i < nbins; i += 256) {
        loff[i]  = base[i] + off[(size_t)b * nbins + i];
        lrank[i] = 0u;
    }
    __syncthreads();
    const int chunk = b * BLK_E;
#pragma unroll
    for (int i = 0; i < EPB; ++i) {
        const int e = chunk + i * 256 + t;
        if (e < n_edges) {
            const unsigned row = (unsigned)ei[e];
            const unsigned col = (unsigned)ei[n_edges + e];
            const unsigned bin = col >> BIN_SHIFT;
            const unsigned r   = atomicAdd(&lrank[bin], 1u);   // LDS only
            rec[loff[bin] + r] = make_uint2((row << 16) | col, (unsigned)e);
        }
    }
}

// ---- fused: one block per 64-node bin; MFMA MLP tiles + LDS max accumulator ----
__global__ __launch_bounds__(256) void edge_mlp_fused(
    const unsigned* __restrict__ xbf,   // [N][16] u32 = [N][32] bf16
    const uint2*    __restrict__ rec,   // [E] {(row<<16)|col, e}, bin-grouped
    const float*    __restrict__ ea,
    const unsigned* __restrict__ w1s,   // [12][64] x 16B frags
    const unsigned* __restrict__ w2s,   // [4][64] x 16B frags
    const float*    __restrict__ b1,
    const float*    __restrict__ b2,
    const float*    __restrict__ x,
    const unsigned* __restrict__ base,  // [nbins+1]
    float*          __restrict__ out,   // [N][32] f32 (fully written here)
    int n_edges, int n_nodes)
{
    __shared__ alignas(16) unsigned short Albs[BM * ASTR];
    __shared__ alignas(16) unsigned short Hlds[BM * HSTR];
    __shared__ unsigned accK[BINW * OUTD];   // monotone-encoded f32 max
    __shared__ unsigned rcsE[BM];
    __shared__ unsigned rcsR[BM];
    __shared__ unsigned rcsC[BM];

    const int t    = threadIdx.x;
    const int lane = t & 63;
    const int wave = t >> 6;
    const int bin  = blockIdx.x;
    const int n0   = bin << BIN_SHIFT;

    const unsigned sbeg = base[bin];
    const unsigned send = base[bin + 1];

    // weight fragments + biases (registers, once)
    short8 w1f[12];
#pragma unroll
    for (int ti = 0; ti < 12; ++ti)
        w1f[ti] = *reinterpret_cast<const short8*>(w1s + (size_t)(ti * 64 + lane) * 4);
    short8 w2f[4];
#pragma unroll
    for (int ti = 0; ti < 4; ++ti)
        w2f[ti] = *reinterpret_cast<const short8*>(w2s + (size_t)(ti * 64 + lane) * 4);
    float bb1[4];
#pragma unroll
    for (int nt = 0; nt < 4; ++nt) bb1[nt] = b1[nt * 16 + (lane & 15)];
    float bb2[2];
#pragma unroll
    for (int nt = 0; nt < 2; ++nt) bb2[nt] = b2[nt * 16 + (lane & 15)];

    // init accumulator with x residual (also covers empty nodes)
#pragma unroll
    for (int k = 0; k < (BINW * OUTD) / 256; ++k) {
        const int idx = t + k * 256;
        const int g   = n0 + (idx >> 5);
        const float r = (g < n_nodes) ? x[(size_t)g * XD + (idx & 31)] : 0.0f;
        accK[idx] = encf(r);
    }

    const int ntile = (int)(send - sbeg + BM - 1) / BM;
    for (int tile = 0; tile < ntile; ++tile) {
        __syncthreads();   // protect rcs/Albs/Hlds/accK from previous iteration

        if (t < BM) {
            unsigned p = sbeg + tile * BM + t;
            if (p >= send) p = send - 1;            // duplicate pad; max-idempotent
            const uint2 q = rec[p];
            rcsE[t] = q.y; rcsR[t] = q.x >> 16; rcsC[t] = q.x & 0xffffu;
        }
        __syncthreads();

        // stage A[:, 0:64]: endpoint rows (thread = (edge m, side))
        {
            const int m    = t & 127;
            const int side = t >> 7;                 // 0 -> x[row], 1 -> x[col]
            const unsigned id = side ? rcsC[m] : rcsR[m];
            const uint4* src = reinterpret_cast<const uint4*>(xbf + (size_t)id * 16);
#pragma unroll
            for (int q = 0; q < 4; ++q)
                *reinterpret_cast<uint4*>(&Albs[m * ASTR + side * 32 + q * 8]) = src[q];
        }
        // stage A[:, 64:96]: ea rows by edge id, f32->bf16
        {
#pragma unroll
            for (int i = 0; i < 4; ++i) {
                const int f = t + i * 256;
                const int m = f >> 3;
                const int c = (f & 7) * 4;
                const unsigned e = rcsE[m];
                const floatx4 d = __builtin_nontemporal_load(
                    reinterpret_cast<const floatx4*>(ea + (size_t)e * 32 + c));
                uint2 pk;
                pk.x = f2bf(d.x) | (f2bf(d.y) << 16);
                pk.y = f2bf(d.z) | (f2bf(d.w) << 16);
                *reinterpret_cast<uint2*>(&Albs[m * ASTR + 64 + c]) = pk;
            }
        }
        __syncthreads();

        // layer 1: [128x96] @ [96x64]
        f32x4 acc1[2][4];
#pragma unroll
        for (int mi = 0; mi < 2; ++mi)
#pragma unroll
            for (int nt = 0; nt < 4; ++nt) acc1[mi][nt] = (f32x4){0.f, 0.f, 0.f, 0.f};
#pragma unroll
        for (int ks = 0; ks < 3; ++ks) {
#pragma unroll
            for (int mi = 0; mi < 2; ++mi) {
                const int mt = wave * 2 + mi;
                short8 afrag = *reinterpret_cast<const short8*>(
                    &Albs[(mt * 16 + (lane & 15)) * ASTR + ks * 32 + ((lane >> 4) << 3)]);
#pragma unroll
                for (int nt = 0; nt < 4; ++nt)
                    acc1[mi][nt] = __builtin_amdgcn_mfma_f32_16x16x32_bf16(
                        afrag, w1f[nt * 3 + ks], acc1[mi][nt], 0, 0, 0);
            }
        }

        // bias + ReLU -> H (bf16, LDS). C layout: col=lane&15, row=(lane>>4)*4+r.
#pragma unroll
        for (int mi = 0; mi < 2; ++mi) {
            const int mt = wave * 2 + mi;
#pragma unroll
            for (int nt = 0; nt < 4; ++nt)
#pragma unroll
                for (int r = 0; r < 4; ++r) {
                    const float h = fmaxf(acc1[mi][nt][r] + bb1[nt], 0.0f);
                    Hlds[(mt * 16 + ((lane >> 4) << 2) + r) * HSTR + nt * 16 + (lane & 15)] =
                        (unsigned short)f2bf(h);
                }
        }
        __syncthreads();

        // layer 2: [128x64] @ [64x32]
        f32x4 acc2[2][2];
#pragma unroll
        for (int mi = 0; mi < 2; ++mi)
#pragma unroll
            for (int nt = 0; nt < 2; ++nt) acc2[mi][nt] = (f32x4){0.f, 0.f, 0.f, 0.f};
#pragma unroll
        for (int ks = 0; ks < 2; ++ks) {
#pragma unroll
            for (int mi = 0; mi < 2; ++mi) {
                const int mt = wave * 2 + mi;
                short8 hfrag = *reinterpret_cast<const short8*>(
                    &Hlds[(mt * 16 + (lane & 15)) * HSTR + ks * 32 + ((lane >> 4) << 3)]);
#pragma unroll
                for (int nt = 0; nt < 2; ++nt)
                    acc2[mi][nt] = __builtin_amdgcn_mfma_f32_16x16x32_bf16(
                        hfrag, w2f[nt * 2 + ks], acc2[mi][nt], 0, 0, 0);
            }
        }

        // epilogue: bias + LDS atomicMax straight from MFMA regs
#pragma unroll
        for (int mi = 0; mi < 2; ++mi) {
            const int mt = wave * 2 + mi;
#pragma unroll
            for (int nt = 0; nt < 2; ++nt)
#pragma unroll
                for (int r = 0; r < 4; ++r) {
                    const int row = mt * 16 + ((lane >> 4) << 2) + r;
                    const float val = acc2[mi][nt][r] + bb2[nt];
                    const int ln = (int)rcsC[row] - n0;      // in [0,64)
                    atomicMax(&accK[ln * OUTD + nt * 16 + (lane & 15)], encf(val));
                }
        }
    }

    __syncthreads();
    // final: decode and store (each node written exactly once -> deterministic)
#pragma unroll
    for (int k = 0; k < (BINW * OUTD) / 256; ++k) {
        const int idx = t + k * 256;
        const int g   = n0 + (idx >> 5);
        if (g < n_nodes)
            out[(size_t)g * OUTD + (idx & 31)] = decf(accK[idx]);
    }
}

extern "C" void kernel_launch(void* const* d_in, const int* in_sizes, int n_in,
                              void* d_out, int out_size, void* d_ws, size_t ws_size,
                              hipStream_t stream)
{
    const float* x  = (const float*)d_in[0];
    const int*   ei = (const int*)  d_in[1];
    const float* ea = (const float*)d_in[2];
    const float* W1 = (const float*)d_in[3];
    const float* b1 = (const float*)d_in[4];
    const float* W2 = (const float*)d_in[5];
    const float* b2 = (const float*)d_in[6];
    float* out = (float*)d_out;

    const int n_nodes = in_sizes[0] / XD;
    const int n_edges = in_sizes[2] / 32;
    const int nbins   = (n_nodes + BINW - 1) >> BIN_SHIFT;      // 782
    const int nblk    = (n_edges + BLK_E - 1) / BLK_E;          // 98 (<=128)

    // ws: cnt[nblk*nbins] | off[nblk*nbins] | totals[nbins] | base[nbins+1] |
    //     rec[E] uint2 | xbf[N*16 u32] | w1s | w2s
    size_t off_b = 0;
    unsigned* cnt    = (unsigned*)((char*)d_ws + off_b); off_b += (size_t)nblk * nbins * 4;
    unsigned* offm   = (unsigned*)((char*)d_ws + off_b); off_b += (size_t)nblk * nbins * 4;
    unsigned* totals = (unsigned*)((char*)d_ws + off_b); off_b += (size_t)nbins * 4;
    unsigned* basep  = (unsigned*)((char*)d_ws + off_b); off_b += (size_t)(nbins + 1) * 4;
    off_b = (off_b + 15) & ~(size_t)15;
    uint2*    rec    = (uint2*)   ((char*)d_ws + off_b); off_b += (size_t)n_edges * 8;
    unsigned* xbf    = (unsigned*)((char*)d_ws + off_b); off_b += (size_t)n_nodes * 16 * 4;
    unsigned* w1s    = (unsigned*)((char*)d_ws + off_b); off_b += 768 * 16;
    unsigned* w2s    = (unsigned*)((char*)d_ws + off_b);

    const int total8 = n_nodes * XD / 8;

    prep<<<(max(total8, 1024) + 255) / 256, 256, 0, stream>>>(x, xbf, W1, W2, w1s, w2s, total8);
    bin_hist<<<nblk, 256, 0, stream>>>(ei, cnt, n_edges, nbins);
    bin_off<<<nbins, 128, 0, stream>>>(cnt, offm, totals, nblk, nbins);
    base_scan<<<1, 256, 0, stream>>>(totals, basep, nbins);
    bin_write<<<nblk, 256, 0, stream>>>(ei, offm, basep, rec, n_edges, nbins);
    edge_mlp_fused<<<nbins, 256, 0, stream>>>(
        xbf, rec, ea, w1s, w2s, b1, b2, x, basep, out, n_edges, n_nodes);
}